// Round 10
// baseline (4265.189 us; speedup 1.0000x reference)
//
#include <hip/hip_runtime.h>
#include <stdint.h>

// Problem constants
#define TT 256      // timesteps per phase
#define BB 256      // batch
#define II 128      // input dim
#define SS 256      // state dim
#define NSTEP (2*TT)
#define NBLKG 64    // 64 blocks x 4 waves = 256 wave-roles (proven launch shape)

typedef _Float16 h16;
typedef _Float16 half8 __attribute__((ext_vector_type(8)));
typedef float f32x4 __attribute__((ext_vector_type(4)));
typedef unsigned int u32x4 __attribute__((ext_vector_type(4)));

// Exchange: [parity][team][row 0..15][col_pair 0..127] of u64
//   u64 = { hi: step tag, lo: 2 x fp16 (even col in low half) }
// Tag-in-data, aligned-8B single-copy atomic (r7/r9-proven). Wave-granular
// lap safety: a wave publishes s_{n+2} only after gathering ALL of s_{n+1},
// which requires every team wave to have published s_{n+1}, which happens
// only after each finished reading s_n. Memset zeroes both parities; tag 0
// with zero data == s_0, so step 1's gather needs no special case.
#define XROW 128
#define XTEAM (16 * XROW)        // 2048 u64 per team
#define XPAR  (16 * XTEAM)       // 32768 u64 per parity

__device__ __forceinline__ float sigmoidf_(float z) {
    return __builtin_amdgcn_rcpf(1.0f + __expf(-z));
}
__device__ __forceinline__ float tanhf_(float z) {
    return 1.0f - 2.0f * __builtin_amdgcn_rcpf(1.0f + __expf(2.0f * z));
}

__device__ __forceinline__ void st_ag64(uint64_t* p, uint64_t v) {
    __hip_atomic_store(p, v, __ATOMIC_RELAXED, __HIP_MEMORY_SCOPE_AGENT);
}

// 16 independent 8B device-coherent loads, offsets kc*128 + j*8 (kc,j in 0..3).
// _nowait variant lets a second block's loads join the same vmcnt window.
#define LD16_BODY(SUFFIX)                                                   \
    asm volatile(                                                           \
        "global_load_dwordx2 %0,  %16, off sc1\n\t"                         \
        "global_load_dwordx2 %1,  %16, off offset:8 sc1\n\t"                \
        "global_load_dwordx2 %2,  %16, off offset:16 sc1\n\t"               \
        "global_load_dwordx2 %3,  %16, off offset:24 sc1\n\t"               \
        "global_load_dwordx2 %4,  %16, off offset:128 sc1\n\t"              \
        "global_load_dwordx2 %5,  %16, off offset:136 sc1\n\t"              \
        "global_load_dwordx2 %6,  %16, off offset:144 sc1\n\t"              \
        "global_load_dwordx2 %7,  %16, off offset:152 sc1\n\t"              \
        "global_load_dwordx2 %8,  %16, off offset:256 sc1\n\t"              \
        "global_load_dwordx2 %9,  %16, off offset:264 sc1\n\t"              \
        "global_load_dwordx2 %10, %16, off offset:272 sc1\n\t"              \
        "global_load_dwordx2 %11, %16, off offset:280 sc1\n\t"              \
        "global_load_dwordx2 %12, %16, off offset:384 sc1\n\t"              \
        "global_load_dwordx2 %13, %16, off offset:392 sc1\n\t"              \
        "global_load_dwordx2 %14, %16, off offset:400 sc1\n\t"              \
        "global_load_dwordx2 %15, %16, off offset:408 sc1" SUFFIX           \
        : "=&v"(v[0]), "=&v"(v[1]), "=&v"(v[2]), "=&v"(v[3]),               \
          "=&v"(v[4]), "=&v"(v[5]), "=&v"(v[6]), "=&v"(v[7]),               \
          "=&v"(v[8]), "=&v"(v[9]), "=&v"(v[10]), "=&v"(v[11]),             \
          "=&v"(v[12]), "=&v"(v[13]), "=&v"(v[14]), "=&v"(v[15])            \
        : "v"(p) : "memory")

__device__ __forceinline__ void ld16_sc1_nowait(const uint64_t* p, uint64_t* v) {
    LD16_BODY("");
}
__device__ __forceinline__ void ld16_sc1_wait(const uint64_t* p, uint64_t* v) {
    LD16_BODY("\n\ts_waitcnt vmcnt(0)");
}

struct Ptrs {
    const float *x;
    const float *Wi, *Ui, *Bi, *Wf, *Uf, *Bf, *Wo, *Uo, *Bo, *Wg, *Ug, *Bg;
    float* out;
    uint32_t* ws;
};

__global__ __launch_bounds__(256, 1) void lstm_wave(Ptrs p) {
    const int tid  = threadIdx.x;
    const int wid  = tid >> 6;             // 4 independent wave-roles per block
    const int lane = tid & 63;
    const int role = blockIdx.x * 4 + wid; // 0..255
    const int team = role >> 4;            // batch rows [team*16, +16)
    const int cb   = role & 15;            // state cols [cb*16, +16)
    const int r0   = team * 16;
    const int c0   = cb * 16;
    const int lrow = lane & 15;            // A-row / C-col for this lane
    const int lgrp = lane >> 4;            // 0..3
    const int lk8  = lgrp * 8;             // k sub-offset within 32-chunk

    uint64_t* xch   = (uint64_t*)p.ws;
    uint64_t* slot0 = xch + (size_t)team * XTEAM;          // parity 0
    uint64_t* slot1 = xch + XPAR + (size_t)team * XTEAM;   // parity 1

    const float* Uptr[4] = {p.Ui, p.Uf, p.Uo, p.Ug};
    const float* Wptr[4] = {p.Wi, p.Wf, p.Wo, p.Wg};
    const float* Bptr[4] = {p.Bi, p.Bf, p.Bo, p.Bg};

    // ---- preload ALL 4 gates' B-fragments (registers/AGPRs; step-invariant)
    // B (16x16x32): lane holds B[k=(lane>>4)*8+q][col=lane&15]  (r9-proven)
    half8 bU[4][8];
#pragma unroll
    for (int g = 0; g < 4; ++g) {
        const float* Ug = Uptr[g];
#pragma unroll
        for (int kc = 0; kc < 8; ++kc)
#pragma unroll
            for (int q = 0; q < 8; ++q)
                bU[g][kc][q] = (h16)Ug[(size_t)(kc * 32 + lk8 + q) * SS + c0 + lrow];
    }
    half8 bW[4][4];
#pragma unroll
    for (int g = 0; g < 4; ++g) {
        const float* Wg = Wptr[g];
#pragma unroll
        for (int kc = 0; kc < 4; ++kc)
#pragma unroll
            for (int q = 0; q < 8; ++q)
                bW[g][kc][q] = (h16)Wg[(size_t)(kc * 32 + lk8 + q) * SS + c0 + lrow];
    }
    float bias[4];
#pragma unroll
    for (int g = 0; g < 4; ++g) bias[g] = Bptr[g][c0 + lrow];

    // cell state: lane owns cells (row = lgrp*4+q, col = lrow), q=0..3
    float cst[4] = {0.f, 0.f, 0.f, 0.f};

    // x A-fragment source for step 1 (x_0), issued up front
    float4 xv[8];
    {
        const float* xp = p.x + ((size_t)0 * BB + r0 + lrow) * II;
#pragma unroll
        for (int kc = 0; kc < 4; ++kc) {
            xv[2*kc]   = ((const float4*)(xp + kc * 32 + lk8))[0];
            xv[2*kc+1] = ((const float4*)(xp + kc * 32 + lk8))[1];
        }
    }

    for (int n = 1; n <= NSTEP; ++n) {
        const bool enc = (n <= TT);

        // ---- spin-gather s_{n-1}: 32 loads in flight, ONE wait per pass ----
        const uint32_t want = (uint32_t)(n - 1);
        const uint64_t* gb = (((n - 1) & 1) ? slot1 : slot0)
                           + (size_t)lrow * XROW + lgrp * 4;
        uint64_t gv[32];
        ld16_sc1_nowait(gb, gv);
        ld16_sc1_wait(gb + 64, gv + 16);
        for (;;) {
            bool ok = true;
#pragma unroll
            for (int i = 0; i < 32; ++i)
                ok = ok && ((uint32_t)(gv[i] >> 32) == want);
            if (__builtin_expect(ok, 1)) break;
            ld16_sc1_nowait(gb, gv);
            ld16_sc1_wait(gb + 64, gv + 16);
        }

        // ---- s @ U: 32 MFMAs, 4 independent chains ----
        f32x4 acc[4];
#pragma unroll
        for (int g = 0; g < 4; ++g) acc[g] = (f32x4){0.f, 0.f, 0.f, 0.f};
#pragma unroll
        for (int kc = 0; kc < 8; ++kc) {
            u32x4 t;
            t.x = (uint32_t)gv[kc*4+0]; t.y = (uint32_t)gv[kc*4+1];
            t.z = (uint32_t)gv[kc*4+2]; t.w = (uint32_t)gv[kc*4+3];
            half8 a = __builtin_bit_cast(half8, t);
#pragma unroll
            for (int g = 0; g < 4; ++g)
                acc[g] = __builtin_amdgcn_mfma_f32_16x16x32_f16(a, bU[g][kc], acc[g], 0, 0, 0);
        }

        // ---- x @ W (encode only; xv loaded during previous step) ----
        if (enc) {
#pragma unroll
            for (int kc = 0; kc < 4; ++kc) {
                half8 xa;
                xa[0] = (h16)xv[2*kc].x;   xa[1] = (h16)xv[2*kc].y;
                xa[2] = (h16)xv[2*kc].z;   xa[3] = (h16)xv[2*kc].w;
                xa[4] = (h16)xv[2*kc+1].x; xa[5] = (h16)xv[2*kc+1].y;
                xa[6] = (h16)xv[2*kc+1].z; xa[7] = (h16)xv[2*kc+1].w;
#pragma unroll
                for (int g = 0; g < 4; ++g)
                    acc[g] = __builtin_amdgcn_mfma_f32_16x16x32_f16(xa, bW[g][kc], acc[g], 0, 0, 0);
            }
        }

        // ---- gates + state update, in-register on C/D fragments ----
        float sv[4], ov[4];
#pragma unroll
        for (int q = 0; q < 4; ++q) {
            float zi = acc[0][q] + bias[0];
            float zf = acc[1][q] + bias[1];
            float zo = acc[2][q] + bias[2];
            float zg = acc[3][q] + bias[3];
            float ig = sigmoidf_(zi), fg = sigmoidf_(zf);
            float og = sigmoidf_(zo), gg = tanhf_(zg);
            cst[q] = cst[q] * fg + gg * ig;
            sv[q] = tanhf_(cst[q]) * og;
            ov[q] = og;
        }

        // ---- publish s_n: tagged u64, fire-and-forget (critical path) ----
        if (n < NSTEP) {
            uint64_t* pb = ((n & 1) ? slot1 : slot0);
            const uint64_t tag = (uint64_t)(uint32_t)n << 32;
#pragma unroll
            for (int q = 0; q < 4; ++q) {
                float so = __shfl_xor(sv[q], 1);
                if ((lane & 1) == 0) {
                    uint16_t lo = __builtin_bit_cast(uint16_t, (h16)sv[q]);
                    uint16_t hi = __builtin_bit_cast(uint16_t, (h16)so);
                    uint64_t pk = tag | (uint64_t)((uint32_t)lo | ((uint32_t)hi << 16));
                    st_ag64(pb + (size_t)(lgrp * 4 + q) * XROW + (c0 >> 1) + (lrow >> 1), pk);
                }
            }
        }

        // ---- off-critical-path: output store + next x-tile issue ----
        if (!enc) {
            const int d = n - TT - 1;
#pragma unroll
            for (int q = 0; q < 4; ++q)
                p.out[((size_t)d * BB + r0 + lgrp * 4 + q) * SS + c0 + lrow] = ov[q];
        }
        if (n < TT) {
            const float* xp = p.x + ((size_t)n * BB + r0 + lrow) * II;
#pragma unroll
            for (int kc = 0; kc < 4; ++kc) {
                xv[2*kc]   = ((const float4*)(xp + kc * 32 + lk8))[0];
                xv[2*kc+1] = ((const float4*)(xp + kc * 32 + lk8))[1];
            }
        }
    }
}

extern "C" void kernel_launch(void* const* d_in, const int* in_sizes, int n_in,
                              void* d_out, int out_size, void* d_ws, size_t ws_size,
                              hipStream_t stream) {
    Ptrs p;
    p.x  = (const float*)d_in[0];
    p.Wi = (const float*)d_in[1];  p.Ui = (const float*)d_in[2];  p.Bi = (const float*)d_in[3];
    p.Wf = (const float*)d_in[4];  p.Uf = (const float*)d_in[5];  p.Bf = (const float*)d_in[6];
    p.Wo = (const float*)d_in[7];  p.Uo = (const float*)d_in[8];  p.Bo = (const float*)d_in[9];
    p.Wg = (const float*)d_in[10]; p.Ug = (const float*)d_in[11]; p.Bg = (const float*)d_in[12];
    p.out = (float*)d_out;
    p.ws  = (uint32_t*)d_ws;

    // zero tags each launch: s_0 (tag 0, zero data) becomes valid; replay-safe
    hipMemsetAsync(d_ws, 0, (size_t)2 * XPAR * sizeof(uint64_t), stream);

    // Proven 64x256 coop shape; plain-launch fallback (protocol needs only
    // de-facto co-residency of 64 blocks on 256 CUs, no grid primitives).
    void* args[] = {&p};
    hipError_t e = hipLaunchCooperativeKernel(lstm_wave, dim3(NBLKG), dim3(256),
                                              args, 0, stream);
    if (e != hipSuccess) {
        hipLaunchKernelGGL(lstm_wave, dim3(NBLKG), dim3(256), 0, stream, p);
    }
}

// Round 11
// 2256.384 us; speedup vs baseline: 1.8903x; 1.8903x over previous
//
#include <hip/hip_runtime.h>
#include <stdint.h>

// Problem constants
#define TT 256      // timesteps per phase
#define BB 256      // batch
#define II 128      // input dim
#define SS 256      // state dim
#define NSTEP (2*TT)
#define NBLKG 256   // 256 blocks x 1 wave = 256 wave-roles, 1 block/CU

typedef _Float16 h16;
typedef _Float16 half8 __attribute__((ext_vector_type(8)));
typedef float f32x4 __attribute__((ext_vector_type(4)));
typedef unsigned int u32x4 __attribute__((ext_vector_type(4)));

// Exchange: [parity][team][row 0..15][col_pair 0..127] of u64
//   u64 = { hi: step tag, lo: 2 x fp16 (even col in low half) }
// Tag-in-data, aligned-8B single-copy atomic (r7/r9/r10-proven). Lap safety:
// a wave publishes s_{n+2} only after gathering ALL of s_{n+1}, which
// requires every team wave to have published s_{n+1}, which happens only
// after each finished reading s_n. Memset zeroes both parities; tag 0 with
// zero data == s_0, so step 1's gather needs no special case.
#define XROW 128
#define XTEAM (16 * XROW)        // 2048 u64 per team
#define XPAR  (16 * XTEAM)       // 32768 u64 per parity

__device__ __forceinline__ float sigmoidf_(float z) {
    return __builtin_amdgcn_rcpf(1.0f + __expf(-z));
}
__device__ __forceinline__ float tanhf_(float z) {
    return 1.0f - 2.0f * __builtin_amdgcn_rcpf(1.0f + __expf(2.0f * z));
}

__device__ __forceinline__ void st_ag64(uint64_t* p, uint64_t v) {
    __hip_atomic_store(p, v, __ATOMIC_RELAXED, __HIP_MEMORY_SCOPE_AGENT);
}

// 16 independent 8B device-coherent loads, offsets kc*128 + j*8 (kc,j in 0..3).
#define LD16_BODY(SUFFIX)                                                   \
    asm volatile(                                                           \
        "global_load_dwordx2 %0,  %16, off sc1\n\t"                         \
        "global_load_dwordx2 %1,  %16, off offset:8 sc1\n\t"                \
        "global_load_dwordx2 %2,  %16, off offset:16 sc1\n\t"               \
        "global_load_dwordx2 %3,  %16, off offset:24 sc1\n\t"               \
        "global_load_dwordx2 %4,  %16, off offset:128 sc1\n\t"              \
        "global_load_dwordx2 %5,  %16, off offset:136 sc1\n\t"              \
        "global_load_dwordx2 %6,  %16, off offset:144 sc1\n\t"              \
        "global_load_dwordx2 %7,  %16, off offset:152 sc1\n\t"              \
        "global_load_dwordx2 %8,  %16, off offset:256 sc1\n\t"              \
        "global_load_dwordx2 %9,  %16, off offset:264 sc1\n\t"              \
        "global_load_dwordx2 %10, %16, off offset:272 sc1\n\t"              \
        "global_load_dwordx2 %11, %16, off offset:280 sc1\n\t"              \
        "global_load_dwordx2 %12, %16, off offset:384 sc1\n\t"              \
        "global_load_dwordx2 %13, %16, off offset:392 sc1\n\t"              \
        "global_load_dwordx2 %14, %16, off offset:400 sc1\n\t"              \
        "global_load_dwordx2 %15, %16, off offset:408 sc1" SUFFIX           \
        : "=&v"(v[0]), "=&v"(v[1]), "=&v"(v[2]), "=&v"(v[3]),               \
          "=&v"(v[4]), "=&v"(v[5]), "=&v"(v[6]), "=&v"(v[7]),               \
          "=&v"(v[8]), "=&v"(v[9]), "=&v"(v[10]), "=&v"(v[11]),             \
          "=&v"(v[12]), "=&v"(v[13]), "=&v"(v[14]), "=&v"(v[15])            \
        : "v"(p) : "memory")

__device__ __forceinline__ void ld16_sc1_nowait(const uint64_t* p, uint64_t* v) {
    LD16_BODY("");
}
__device__ __forceinline__ void ld16_sc1_wait(const uint64_t* p, uint64_t* v) {
    LD16_BODY("\n\ts_waitcnt vmcnt(0)");
}

struct Ptrs {
    const float *x;
    const float *Wi, *Ui, *Bi, *Wf, *Uf, *Bf, *Wo, *Uo, *Bo, *Wg, *Ug, *Bg;
    float* out;
    uint32_t* ws;
};

__global__ __launch_bounds__(64, 1) void lstm_wave(Ptrs p) {
    const int lane = threadIdx.x;          // one wave per block
    const int role = blockIdx.x;           // 0..255
    const int team = role >> 4;            // batch rows [team*16, +16)
    const int cb   = role & 15;            // state cols [cb*16, +16)
    const int r0   = team * 16;
    const int c0   = cb * 16;
    const int lrow = lane & 15;            // A-row / C-col for this lane
    const int lgrp = lane >> 4;            // 0..3
    const int lk8  = lgrp * 8;             // k sub-offset within 32-chunk

    // 96 KB LDS: forces 1 block/CU (2*96 KB > 160 KB pool) so the 256 roles
    // spread across all 256 CUs (fixes r10's 4-waves-per-CU port contention).
    // Pinned against DCE (r3 lesson) by a real store + address escape.
    __shared__ __align__(16) uint32_t spread_pad[24576];
    spread_pad[lane] = (uint32_t)lane;
    asm volatile("" :: "v"(&spread_pad[lane]) : "memory");

    uint64_t* xch   = (uint64_t*)p.ws;
    uint64_t* slot0 = xch + (size_t)team * XTEAM;          // parity 0
    uint64_t* slot1 = xch + XPAR + (size_t)team * XTEAM;   // parity 1

    const float* Uptr[4] = {p.Ui, p.Uf, p.Uo, p.Ug};
    const float* Wptr[4] = {p.Wi, p.Wf, p.Wo, p.Wg};
    const float* Bptr[4] = {p.Bi, p.Bf, p.Bo, p.Bg};

    // ---- preload ALL 4 gates' B-fragments (step-invariant registers) ----
    // B (16x16x32): lane holds B[k=(lane>>4)*8+q][col=lane&15]  (r9/r10-proven)
    half8 bU[4][8];
#pragma unroll
    for (int g = 0; g < 4; ++g) {
        const float* Ug = Uptr[g];
#pragma unroll
        for (int kc = 0; kc < 8; ++kc)
#pragma unroll
            for (int q = 0; q < 8; ++q)
                bU[g][kc][q] = (h16)Ug[(size_t)(kc * 32 + lk8 + q) * SS + c0 + lrow];
    }
    half8 bW[4][4];
#pragma unroll
    for (int g = 0; g < 4; ++g) {
        const float* Wg = Wptr[g];
#pragma unroll
        for (int kc = 0; kc < 4; ++kc)
#pragma unroll
            for (int q = 0; q < 8; ++q)
                bW[g][kc][q] = (h16)Wg[(size_t)(kc * 32 + lk8 + q) * SS + c0 + lrow];
    }
    float bias[4];
#pragma unroll
    for (int g = 0; g < 4; ++g) bias[g] = Bptr[g][c0 + lrow];

    // cell state: lane owns cells (row = lgrp*4+q, col = lrow), q=0..3
    float cst[4] = {0.f, 0.f, 0.f, 0.f};

    // x A-fragment source for step 1 (x_0), issued up front
    float4 xv[8];
    {
        const float* xp = p.x + ((size_t)0 * BB + r0 + lrow) * II;
#pragma unroll
        for (int kc = 0; kc < 4; ++kc) {
            xv[2*kc]   = ((const float4*)(xp + kc * 32 + lk8))[0];
            xv[2*kc+1] = ((const float4*)(xp + kc * 32 + lk8))[1];
        }
    }

    for (int n = 1; n <= NSTEP; ++n) {
        const bool enc = (n <= TT);

        // ---- spin-gather s_{n-1}: 32 loads in flight, ONE wait per pass ----
        const uint32_t want = (uint32_t)(n - 1);
        const uint64_t* gb = (((n - 1) & 1) ? slot1 : slot0)
                           + (size_t)lrow * XROW + lgrp * 4;
        uint64_t gv[32];
        ld16_sc1_nowait(gb, gv);
        ld16_sc1_wait(gb + 64, gv + 16);
        for (;;) {
            bool ok = true;
#pragma unroll
            for (int i = 0; i < 32; ++i)
                ok = ok && ((uint32_t)(gv[i] >> 32) == want);
            if (__builtin_expect(ok, 1)) break;
            ld16_sc1_nowait(gb, gv);
            ld16_sc1_wait(gb + 64, gv + 16);
        }

        // ---- s @ U: 32 MFMAs, 4 independent gate chains ----
        f32x4 acc[4];
#pragma unroll
        for (int g = 0; g < 4; ++g) acc[g] = (f32x4){0.f, 0.f, 0.f, 0.f};
#pragma unroll
        for (int kc = 0; kc < 8; ++kc) {
            u32x4 t;
            t.x = (uint32_t)gv[kc*4+0]; t.y = (uint32_t)gv[kc*4+1];
            t.z = (uint32_t)gv[kc*4+2]; t.w = (uint32_t)gv[kc*4+3];
            half8 a = __builtin_bit_cast(half8, t);
#pragma unroll
            for (int g = 0; g < 4; ++g)
                acc[g] = __builtin_amdgcn_mfma_f32_16x16x32_f16(a, bU[g][kc], acc[g], 0, 0, 0);
        }

        // ---- x @ W (encode only; xv loaded during previous step) ----
        if (enc) {
#pragma unroll
            for (int kc = 0; kc < 4; ++kc) {
                half8 xa;
                xa[0] = (h16)xv[2*kc].x;   xa[1] = (h16)xv[2*kc].y;
                xa[2] = (h16)xv[2*kc].z;   xa[3] = (h16)xv[2*kc].w;
                xa[4] = (h16)xv[2*kc+1].x; xa[5] = (h16)xv[2*kc+1].y;
                xa[6] = (h16)xv[2*kc+1].z; xa[7] = (h16)xv[2*kc+1].w;
#pragma unroll
                for (int g = 0; g < 4; ++g)
                    acc[g] = __builtin_amdgcn_mfma_f32_16x16x32_f16(xa, bW[g][kc], acc[g], 0, 0, 0);
            }
        }

        // ---- gates + state update, in-register on C/D fragments ----
        float sv[4], ov[4];
#pragma unroll
        for (int q = 0; q < 4; ++q) {
            float zi = acc[0][q] + bias[0];
            float zf = acc[1][q] + bias[1];
            float zo = acc[2][q] + bias[2];
            float zg = acc[3][q] + bias[3];
            float ig = sigmoidf_(zi), fg = sigmoidf_(zf);
            float og = sigmoidf_(zo), gg = tanhf_(zg);
            cst[q] = cst[q] * fg + gg * ig;
            sv[q] = tanhf_(cst[q]) * og;
            ov[q] = og;
        }

        // ---- publish s_n: tagged u64, fire-and-forget (critical path) ----
        if (n < NSTEP) {
            uint64_t* pb = ((n & 1) ? slot1 : slot0);
            const uint64_t tag = (uint64_t)(uint32_t)n << 32;
#pragma unroll
            for (int q = 0; q < 4; ++q) {
                float so = __shfl_xor(sv[q], 1);
                if ((lane & 1) == 0) {
                    uint16_t lo = __builtin_bit_cast(uint16_t, (h16)sv[q]);
                    uint16_t hi = __builtin_bit_cast(uint16_t, (h16)so);
                    uint64_t pk = tag | (uint64_t)((uint32_t)lo | ((uint32_t)hi << 16));
                    st_ag64(pb + (size_t)(lgrp * 4 + q) * XROW + (c0 >> 1) + (lrow >> 1), pk);
                }
            }
        }

        // ---- off-critical-path: output store + next x-tile issue ----
        if (!enc) {
            const int d = n - TT - 1;
#pragma unroll
            for (int q = 0; q < 4; ++q)
                p.out[((size_t)d * BB + r0 + lgrp * 4 + q) * SS + c0 + lrow] = ov[q];
        }
        if (n < TT) {
            const float* xp = p.x + ((size_t)n * BB + r0 + lrow) * II;
#pragma unroll
            for (int kc = 0; kc < 4; ++kc) {
                xv[2*kc]   = ((const float4*)(xp + kc * 32 + lk8))[0];
                xv[2*kc+1] = ((const float4*)(xp + kc * 32 + lk8))[1];
            }
        }
    }
}

extern "C" void kernel_launch(void* const* d_in, const int* in_sizes, int n_in,
                              void* d_out, int out_size, void* d_ws, size_t ws_size,
                              hipStream_t stream) {
    Ptrs p;
    p.x  = (const float*)d_in[0];
    p.Wi = (const float*)d_in[1];  p.Ui = (const float*)d_in[2];  p.Bi = (const float*)d_in[3];
    p.Wf = (const float*)d_in[4];  p.Uf = (const float*)d_in[5];  p.Bf = (const float*)d_in[6];
    p.Wo = (const float*)d_in[7];  p.Uo = (const float*)d_in[8];  p.Bo = (const float*)d_in[9];
    p.Wg = (const float*)d_in[10]; p.Ug = (const float*)d_in[11]; p.Bg = (const float*)d_in[12];
    p.out = (float*)d_out;
    p.ws  = (uint32_t*)d_ws;

    // zero tags each launch: s_0 (tag 0, zero data) becomes valid; replay-safe
    hipMemsetAsync(d_ws, 0, (size_t)2 * XPAR * sizeof(uint64_t), stream);

    // Coop launch preferred; plain-launch fallback (r6 lesson: this shape can
    // be rejected silently). 256 single-wave blocks at 1 block/CU are
    // co-resident under either launch path; protocol needs nothing more.
    void* args[] = {&p};
    hipError_t e = hipLaunchCooperativeKernel(lstm_wave, dim3(NBLKG), dim3(64),
                                              args, 0, stream);
    if (e != hipSuccess) {
        hipLaunchKernelGGL(lstm_wave, dim3(NBLKG), dim3(64), 0, stream, p);
    }
}